// Round 2
// baseline (4600.385 us; speedup 1.0000x reference)
//
#include <hip/hip_runtime.h>
#include <hip/hip_bf16.h>
#include <cstddef>

// Problem constants: B=8, C=512, H=96, W=96, NHEADS=8, dh=64.
// Token view: M = B*W*H = 73728 tokens, token m = bb*9216 + ww*96 + hh.
#define NB 8
#define NC 512
#define NH 96
#define NW 96
#define HWSZ 9216          // 96*96
#define CHW 4718592ull     // 512*96*96
#define MTOK 73728         // 8*96*96

// ---------------------------------------------------------------------------
// Transpose: x[b,c,h,w] -> T[m, c]  (m = b*9216 + w*96 + h)
// ---------------------------------------------------------------------------
__global__ __launch_bounds__(256) void bchw_to_tok_k(const float* __restrict__ x,
                                                     float* __restrict__ T) {
  __shared__ float s[32][33];
  const int tx = threadIdx.x;       // 0..31
  const int ty = threadIdx.y;       // 0..7
  const int cc0 = (blockIdx.x / 3) * 32;
  const int ww0 = (blockIdx.x % 3) * 32;
  const int hh = blockIdx.y;
  const int bb = blockIdx.z;
#pragma unroll
  for (int i = 0; i < 4; ++i) {
    // load: channels along ty (rows), width along tx (coalesced)
    s[ty + 8 * i][tx] =
        x[(((size_t)bb * NC + cc0 + ty + 8 * i) * NH + hh) * NW + ww0 + tx];
  }
  __syncthreads();
#pragma unroll
  for (int i = 0; i < 4; ++i) {
    // store: channel along tx (coalesced into token row)
    T[((size_t)bb * HWSZ + (size_t)(ww0 + ty + 8 * i) * NH + hh) * NC + cc0 + tx] =
        s[tx][ty + 8 * i];
  }
}

// Inverse: Y[b,c,h,w] = T[m, c]
__global__ __launch_bounds__(256) void tok_to_bchw_k(const float* __restrict__ T,
                                                     float* __restrict__ Y) {
  __shared__ float s[32][33];
  const int tx = threadIdx.x;
  const int ty = threadIdx.y;
  const int cc0 = (blockIdx.x / 3) * 32;
  const int ww0 = (blockIdx.x % 3) * 32;
  const int hh = blockIdx.y;
  const int bb = blockIdx.z;
#pragma unroll
  for (int i = 0; i < 4; ++i) {
    // load token rows: c along tx (coalesced), w along ty
    s[ty + 8 * i][tx] =
        T[((size_t)bb * HWSZ + (size_t)(ww0 + ty + 8 * i) * NH + hh) * NC + cc0 + tx];
  }
  __syncthreads();
#pragma unroll
  for (int i = 0; i < 4; ++i) {
    // store bchw: w along tx (coalesced)
    Y[(((size_t)bb * NC + cc0 + ty + 8 * i) * NH + hh) * NW + ww0 + tx] =
        s[tx][ty + 8 * i];
  }
}

// ---------------------------------------------------------------------------
// GEMM (NT): Co[M,512] = A[M,512] @ Wt[512,512]^T (+ Add[M,512]) (+ bias[512])
// grid: (M/128, 4); block 256; 8x8 per thread; BK=32.
// ---------------------------------------------------------------------------
__global__ __launch_bounds__(256) void gemm_nt_k(const float* __restrict__ A,
                                                 const float* __restrict__ Wt,
                                                 const float* __restrict__ Add,
                                                 const float* __restrict__ bias,
                                                 float* __restrict__ Co) {
  __shared__ float As[32][132];  // [k][m], +4 pad
  __shared__ float Bs[32][132];  // [k][n]
  const int t = threadIdx.x;
  const int m0 = blockIdx.x * 128;
  const int n0 = blockIdx.y * 128;
  const int tx = t & 15;        // col group
  const int ty = t >> 4;        // row group
  const int lr = t >> 3;        // 0..31 loader row
  const int lk = (t & 7) << 2;  // 0,4,..,28 loader k

  float acc[8][8];
#pragma unroll
  for (int i = 0; i < 8; ++i)
#pragma unroll
    for (int j = 0; j < 8; ++j) acc[i][j] = 0.f;

  for (int k0 = 0; k0 < 512; k0 += 32) {
#pragma unroll
    for (int i = 0; i < 4; ++i) {
      const int row = lr + i * 32;
      float4 va = *(const float4*)&A[(size_t)(m0 + row) * 512 + k0 + lk];
      As[lk + 0][row] = va.x; As[lk + 1][row] = va.y;
      As[lk + 2][row] = va.z; As[lk + 3][row] = va.w;
      float4 vb = *(const float4*)&Wt[(size_t)(n0 + row) * 512 + k0 + lk];
      Bs[lk + 0][row] = vb.x; Bs[lk + 1][row] = vb.y;
      Bs[lk + 2][row] = vb.z; Bs[lk + 3][row] = vb.w;
    }
    __syncthreads();
#pragma unroll
    for (int kk = 0; kk < 32; ++kk) {
      float a[8], b[8];
      *(float4*)&a[0] = *(const float4*)&As[kk][ty * 8];
      *(float4*)&a[4] = *(const float4*)&As[kk][ty * 8 + 4];
      *(float4*)&b[0] = *(const float4*)&Bs[kk][tx * 8];
      *(float4*)&b[4] = *(const float4*)&Bs[kk][tx * 8 + 4];
#pragma unroll
      for (int i = 0; i < 8; ++i)
#pragma unroll
        for (int j = 0; j < 8; ++j) acc[i][j] = fmaf(a[i], b[j], acc[i][j]);
    }
    __syncthreads();
  }

  float bv[8];
#pragma unroll
  for (int j = 0; j < 8; ++j) bv[j] = bias ? bias[n0 + tx * 8 + j] : 0.f;

#pragma unroll
  for (int i = 0; i < 8; ++i) {
    const size_t off = (size_t)(m0 + ty * 8 + i) * 512 + n0 + tx * 8;
    float r[8];
#pragma unroll
    for (int j = 0; j < 8; ++j) r[j] = acc[i][j] + bv[j];
    if (Add) {
      float4 a0 = *(const float4*)&Add[off];
      float4 a1 = *(const float4*)&Add[off + 4];
      r[0] += a0.x; r[1] += a0.y; r[2] += a0.z; r[3] += a0.w;
      r[4] += a1.x; r[5] += a1.y; r[6] += a1.z; r[7] += a1.w;
    }
    float4 v0 = make_float4(r[0], r[1], r[2], r[3]);
    float4 v1 = make_float4(r[4], r[5], r[6], r[7]);
    *(float4*)&Co[off] = v0;
    *(float4*)&Co[off + 4] = v1;
  }
}

// ---------------------------------------------------------------------------
// Attention: per (n, head) block. Q,K,V token-major [73728, 512].
// scores = (Qh @ Kh^T)/8, softmax rows, O = P @ Vh. T=96, dh=64.
// grid (768, 8), block 256. LDS < 64 KB (qs/ks staged; scores overlap them).
// ---------------------------------------------------------------------------
__global__ __launch_bounds__(256) void attn_kernel(const float* __restrict__ Q,
                                                   const float* __restrict__ Km,
                                                   const float* __restrict__ Vm,
                                                   float* __restrict__ O) {
  __shared__ float sm[2 * 96 * 66];  // qs | ks ; later reused for scores (96*97)
  float* qs = sm;
  float* ks = sm + 96 * 66;
  float* ss = sm;
  const int n = blockIdx.x;
  const int hd = blockIdx.y;
  const int t = threadIdx.x;
  const size_t base = (size_t)n * 96 * 512 + (size_t)hd * 64;

  // stage Q,K rows (float2, 2-way-conflict-free with stride 66)
  for (int f = t; f < 3072; f += 256) {
    const int row = f >> 5;
    const int d2 = (f & 31) << 1;
    const size_t g = base + (size_t)row * 512 + d2;
    *(float2*)&qs[row * 66 + d2] = *(const float2*)&Q[g];
    *(float2*)&ks[row * 66 + d2] = *(const float2*)&Km[g];
  }
  __syncthreads();

  // phase 1: scores into registers. i = ty+8*ii (12), j = tx+32*jj (3).
  float sc[12][3];
  {
    const int tx = t & 31, ty = t >> 5;
#pragma unroll
    for (int ii = 0; ii < 12; ++ii) { sc[ii][0] = 0.f; sc[ii][1] = 0.f; sc[ii][2] = 0.f; }
#pragma unroll 8
    for (int d = 0; d < 64; d += 2) {
      const float2 k0 = *(const float2*)&ks[tx * 66 + d];
      const float2 k1 = *(const float2*)&ks[(tx + 32) * 66 + d];
      const float2 k2 = *(const float2*)&ks[(tx + 64) * 66 + d];
#pragma unroll
      for (int ii = 0; ii < 12; ++ii) {
        const float2 qv = *(const float2*)&qs[(ty + 8 * ii) * 66 + d];
        sc[ii][0] += qv.x * k0.x + qv.y * k0.y;
        sc[ii][1] += qv.x * k1.x + qv.y * k1.y;
        sc[ii][2] += qv.x * k2.x + qv.y * k2.y;
      }
    }
  }
  __syncthreads();  // all qs/ks reads done; safe to overwrite with scores
  {
    const int tx = t & 31, ty = t >> 5;
#pragma unroll
    for (int ii = 0; ii < 12; ++ii) {
      ss[(ty + 8 * ii) * 97 + tx] = sc[ii][0] * 0.125f;
      ss[(ty + 8 * ii) * 97 + tx + 32] = sc[ii][1] * 0.125f;
      ss[(ty + 8 * ii) * 97 + tx + 64] = sc[ii][2] * 0.125f;
    }
  }
  __syncthreads();

  // phase 2: softmax, one row per thread (t < 96)
  if (t < 96) {
    float mx = -3.4e38f;
    for (int j = 0; j < 96; ++j) mx = fmaxf(mx, ss[t * 97 + j]);
    float sum = 0.f;
    for (int j = 0; j < 96; ++j) {
      const float e = __expf(ss[t * 97 + j] - mx);
      ss[t * 97 + j] = e;
      sum += e;
    }
    const float inv = 1.f / sum;
    for (int j = 0; j < 96; ++j) ss[t * 97 + j] *= inv;
  }
  __syncthreads();

  // phase 3: O = P @ Vh. d = 2*(t&31), i = ib+8*ii. V from global (L1/L2-resident).
  {
    const int d = (t & 31) << 1;
    const int ib = t >> 5;  // 0..7
    float oc[12][2];
#pragma unroll
    for (int ii = 0; ii < 12; ++ii) { oc[ii][0] = 0.f; oc[ii][1] = 0.f; }
#pragma unroll 4
    for (int j = 0; j < 96; ++j) {
      const float2 pv = *(const float2*)&Vm[base + (size_t)j * 512 + d];
#pragma unroll
      for (int ii = 0; ii < 12; ++ii) {
        const float p = ss[(ib + 8 * ii) * 97 + j];
        oc[ii][0] += p * pv.x;
        oc[ii][1] += p * pv.y;
      }
    }
#pragma unroll
    for (int ii = 0; ii < 12; ++ii)
      *(float2*)&O[base + (size_t)(ib + 8 * ii) * 512 + d] = *(float2*)&oc[ii][0];
  }
}

// ---------------------------------------------------------------------------
// Depthwise 3x3 (SAME) + BatchNorm(eval): y in bchw layout
// ---------------------------------------------------------------------------
__global__ __launch_bounds__(256) void dwconv_bn_k(const float* __restrict__ x,
                                                   const float* __restrict__ w9,
                                                   const float* __restrict__ g,
                                                   const float* __restrict__ bta,
                                                   const float* __restrict__ mu,
                                                   const float* __restrict__ var,
                                                   float* __restrict__ y) {
  const int idx = blockIdx.x * 256 + threadIdx.x;  // < 37748736
  const int wq = idx % 96;
  const int r1 = idx / 96;
  const int hq = r1 % 96;
  const int c = (r1 / 96) & 511;
  const int bq = idx / 4718592;
  const float* xb = x + ((size_t)bq * NC + c) * HWSZ;
  const float* wc = w9 + c * 9;
  float acc = 0.f;
#pragma unroll
  for (int di = -1; di <= 1; ++di) {
    const int h2 = hq + di;
    if (h2 < 0 || h2 > 95) continue;
#pragma unroll
    for (int dj = -1; dj <= 1; ++dj) {
      const int w2 = wq + dj;
      if (w2 < 0 || w2 > 95) continue;
      acc += xb[h2 * 96 + w2] * wc[(di + 1) * 3 + (dj + 1)];
    }
  }
  const float scl = g[c] / sqrtf(var[c] + 1e-5f);
  y[idx] = (acc - mu[c]) * scl + bta[c];
}

// ---------------------------------------------------------------------------
// Pointwise conv (NN GEMM per batch) + ReLU6 + cross-attn residual:
// Out[b,o,p] = clip(sum_c pw[o,c]*Ybn[b,c,p], 0, 6) + CrT[b,o,p]
// grid (72, 4, 8); block 256; 8x8 per thread; BK=32.
// ---------------------------------------------------------------------------
__global__ __launch_bounds__(256) void gemm_pw_k(const float* __restrict__ Wpw,
                                                 const float* __restrict__ Bm,
                                                 const float* __restrict__ CrT,
                                                 float* __restrict__ Out) {
  __shared__ float As[32][132];  // [k][o]
  __shared__ float Bs[32][132];  // [k][p]
  const int t = threadIdx.x;
  const int p0 = blockIdx.x * 128;
  const int o0 = blockIdx.y * 128;
  const size_t bb = blockIdx.z;
  const float* B0 = Bm + bb * CHW;
  const int tx = t & 15;
  const int ty = t >> 4;
  const int lr = t >> 3;
  const int lk = (t & 7) << 2;

  float acc[8][8];
#pragma unroll
  for (int i = 0; i < 8; ++i)
#pragma unroll
    for (int j = 0; j < 8; ++j) acc[i][j] = 0.f;

  for (int k0 = 0; k0 < 512; k0 += 32) {
#pragma unroll
    for (int i = 0; i < 4; ++i) {
      const int row = lr + i * 32;
      float4 va = *(const float4*)&Wpw[(size_t)(o0 + row) * 512 + k0 + lk];
      As[lk + 0][row] = va.x; As[lk + 1][row] = va.y;
      As[lk + 2][row] = va.z; As[lk + 3][row] = va.w;
    }
#pragma unroll
    for (int i = 0; i < 4; ++i) {
      const int f = t + i * 256;
      const int kq = f >> 5;
      const int pq = (f & 31) << 2;
      *(float4*)&Bs[kq][pq] = *(const float4*)&B0[(size_t)(k0 + kq) * HWSZ + p0 + pq];
    }
    __syncthreads();
#pragma unroll
    for (int kk = 0; kk < 32; ++kk) {
      float a[8], b[8];
      *(float4*)&a[0] = *(const float4*)&As[kk][ty * 8];
      *(float4*)&a[4] = *(const float4*)&As[kk][ty * 8 + 4];
      *(float4*)&b[0] = *(const float4*)&Bs[kk][tx * 8];
      *(float4*)&b[4] = *(const float4*)&Bs[kk][tx * 8 + 4];
#pragma unroll
      for (int i = 0; i < 8; ++i)
#pragma unroll
        for (int j = 0; j < 8; ++j) acc[i][j] = fmaf(a[i], b[j], acc[i][j]);
    }
    __syncthreads();
  }

#pragma unroll
  for (int i = 0; i < 8; ++i) {
    const int o = o0 + ty * 8 + i;
    const size_t off = bb * CHW + (size_t)o * HWSZ + p0 + tx * 8;
    const float4 c0 = *(const float4*)&CrT[off];
    const float4 c1 = *(const float4*)&CrT[off + 4];
    float4 v0, v1;
    v0.x = fminf(fmaxf(acc[i][0], 0.f), 6.f) + c0.x;
    v0.y = fminf(fmaxf(acc[i][1], 0.f), 6.f) + c0.y;
    v0.z = fminf(fmaxf(acc[i][2], 0.f), 6.f) + c0.z;
    v0.w = fminf(fmaxf(acc[i][3], 0.f), 6.f) + c0.w;
    v1.x = fminf(fmaxf(acc[i][4], 0.f), 6.f) + c1.x;
    v1.y = fminf(fmaxf(acc[i][5], 0.f), 6.f) + c1.y;
    v1.z = fminf(fmaxf(acc[i][6], 0.f), 6.f) + c1.z;
    v1.w = fminf(fmaxf(acc[i][7], 0.f), 6.f) + c1.w;
    *(float4*)&Out[off] = v0;
    *(float4*)&Out[off + 4] = v1;
  }
}

// ---------------------------------------------------------------------------
// Schedule (4 workspace buffers, 604 MB total; liveness verified):
//  w0=Xt  w1=Kb/KV2/Ybn  w2=Vb/O1/A2  w3=A1/Q2/crT
// ---------------------------------------------------------------------------
extern "C" void kernel_launch(void* const* d_in, const int* in_sizes, int n_in,
                              void* d_out, int out_size, void* d_ws, size_t ws_size,
                              hipStream_t stream) {
  const float* x   = (const float*)d_in[0];
  const float* Wk  = (const float*)d_in[1];
  const float* Wv  = (const float*)d_in[2];
  const float* Wo  = (const float*)d_in[3];
  const float* cWq = (const float*)d_in[4];
  const float* cbq = (const float*)d_in[5];
  const float* cWv = (const float*)d_in[6];
  const float* cWo = (const float*)d_in[7];
  const float* dw  = (const float*)d_in[8];
  const float* bng = (const float*)d_in[9];
  const float* bnb = (const float*)d_in[10];
  const float* bnm = (const float*)d_in[11];
  const float* bnv = (const float*)d_in[12];
  const float* pw  = (const float*)d_in[13];
  float* out = (float*)d_out;
  float* ws = (float*)d_ws;

  const size_t SZ = (size_t)MTOK * NC;  // 37,748,736 floats per buffer
  float* w0 = ws;
  float* w1 = ws + SZ;
  float* w2 = ws + 2 * SZ;
  float* w3 = ws + 3 * SZ;

  const dim3 tb(32, 8);
  const dim3 tg(48, 96, 8);        // transposes
  const dim3 gg(MTOK / 128, 4);    // token GEMMs (576, 4)

  // 1. vqk tokens: w0 = Xt
  bchw_to_tok_k<<<tg, tb, 0, stream>>>(x, w0);
  // 2. K = Xt@Wk^T + Xt -> w1
  gemm_nt_k<<<gg, 256, 0, stream>>>(w0, Wk, w0, nullptr, w1);
  // 3. V = Xt@Wv^T -> w2
  gemm_nt_k<<<gg, 256, 0, stream>>>(w0, Wv, nullptr, nullptr, w2);
  // 4. MSA attention (q = Xt) -> w3 = A1
  attn_kernel<<<dim3(768, 8), 256, 0, stream>>>(w0, w1, w2, w3);
  // 5. KV2 = Xt@cWv^T -> w1  (K dead; Xt last read here)
  gemm_nt_k<<<gg, 256, 0, stream>>>(w0, cWv, nullptr, nullptr, w1);
  // 6. O1 = A1@Wo^T -> w2  (V dead)
  gemm_nt_k<<<gg, 256, 0, stream>>>(w3, Wo, nullptr, nullptr, w2);
  // 7. odd reshape: xp[b,c,h,w] = O1 tokens -> w0  (Xt dead)
  tok_to_bchw_k<<<tg, tb, 0, stream>>>(w2, w0);
  // 8. Q2 = xp_flat@cWq^T + bq -> w3  (A1 dead)
  gemm_nt_k<<<gg, 256, 0, stream>>>(w0, cWq, nullptr, cbq, w3);
  // 9. Cross attention (q=Q2, k=v=KV2) -> w2  (O1 dead)
  attn_kernel<<<dim3(768, 8), 256, 0, stream>>>(w3, w1, w1, w2);
  // 10. CR = A2@cWo^T -> w0  (xp dead)
  gemm_nt_k<<<gg, 256, 0, stream>>>(w2, cWo, nullptr, nullptr, w0);
  // 11. cr to bchw -> w3 = crT  (Q2 dead)
  tok_to_bchw_k<<<tg, tb, 0, stream>>>(w0, w3);
  // 12. depthwise conv + BN -> w1 = Ybn  (KV2 dead)
  dwconv_bn_k<<<147456, 256, 0, stream>>>(x, dw, bng, bnb, bnm, bnv, w1);
  // 13. pointwise + ReLU6 + residual -> out
  gemm_pw_k<<<dim3(72, 4, 8), 256, 0, stream>>>(pw, w1, w3, out);
}

// Round 4
// 3626.713 us; speedup vs baseline: 1.2685x; 1.2685x over previous
//
#include <hip/hip_runtime.h>
#include <hip/hip_bf16.h>
#include <cstddef>

// Problem constants: B=8, C=512, H=96, W=96, NHEADS=8, dh=64.
// Token view: M = B*W*H = 73728 tokens, token m = bb*9216 + ww*96 + hh.
#define NB 8
#define NC 512
#define NH 96
#define NW 96
#define HWSZ 9216          // 96*96
#define CHW 4718592ull     // 512*96*96
#define MTOK 73728         // 8*96*96

typedef __attribute__((ext_vector_type(8))) short bf16x8;
typedef __attribute__((ext_vector_type(4))) float f32x4;
typedef unsigned int uint;
typedef unsigned short ushort;

__device__ inline uint bf16rn(float f) {
  uint v = __float_as_uint(f);
  return (v + 0x7fffu + ((v >> 16) & 1u)) >> 16;  // round-to-nearest-even bf16
}

// ---------------------------------------------------------------------------
// Transpose: x[b,c,h,w] -> T[m, c]  (m = b*9216 + w*96 + h)
// ---------------------------------------------------------------------------
__global__ __launch_bounds__(256) void bchw_to_tok_k(const float* __restrict__ x,
                                                     float* __restrict__ T) {
  __shared__ float s[32][33];
  const int tx = threadIdx.x;       // 0..31
  const int ty = threadIdx.y;       // 0..7
  const int cc0 = (blockIdx.x / 3) * 32;
  const int ww0 = (blockIdx.x % 3) * 32;
  const int hh = blockIdx.y;
  const int bb = blockIdx.z;
#pragma unroll
  for (int i = 0; i < 4; ++i) {
    s[ty + 8 * i][tx] =
        x[(((size_t)bb * NC + cc0 + ty + 8 * i) * NH + hh) * NW + ww0 + tx];
  }
  __syncthreads();
#pragma unroll
  for (int i = 0; i < 4; ++i) {
    T[((size_t)bb * HWSZ + (size_t)(ww0 + ty + 8 * i) * NH + hh) * NC + cc0 + tx] =
        s[tx][ty + 8 * i];
  }
}

// Inverse: Y[b,c,h,w] = T[m, c]
__global__ __launch_bounds__(256) void tok_to_bchw_k(const float* __restrict__ T,
                                                     float* __restrict__ Y) {
  __shared__ float s[32][33];
  const int tx = threadIdx.x;
  const int ty = threadIdx.y;
  const int cc0 = (blockIdx.x / 3) * 32;
  const int ww0 = (blockIdx.x % 3) * 32;
  const int hh = blockIdx.y;
  const int bb = blockIdx.z;
#pragma unroll
  for (int i = 0; i < 4; ++i) {
    s[ty + 8 * i][tx] =
        T[((size_t)bb * HWSZ + (size_t)(ww0 + ty + 8 * i) * NH + hh) * NC + cc0 + tx];
  }
  __syncthreads();
#pragma unroll
  for (int i = 0; i < 4; ++i) {
    Y[(((size_t)bb * NC + cc0 + ty + 8 * i) * NH + hh) * NW + ww0 + tx] =
        s[tx][ty + 8 * i];
  }
}

// ---------------------------------------------------------------------------
// Weight split: W[512,512] fp32 -> Wh (trunc bf16) + Wl (rn bf16 of residual).
// dst layout: matrix mi -> hi at mi*524288, lo at mi*524288+262144 (ushorts).
// ---------------------------------------------------------------------------
__global__ __launch_bounds__(256) void wext_k(const float* __restrict__ W0,
                                              const float* __restrict__ W1,
                                              const float* __restrict__ W2,
                                              const float* __restrict__ W3,
                                              const float* __restrict__ W4,
                                              const float* __restrict__ W5,
                                              const float* __restrict__ W6,
                                              ushort* __restrict__ dst) {
  const float* srcs[7] = {W0, W1, W2, W3, W4, W5, W6};
  const float* s = srcs[blockIdx.y];
  const int i = blockIdx.x * 256 + threadIdx.x;  // < 65536 (float4 units)
  const float4 v = ((const float4*)s)[i];
  const uint u0 = __float_as_uint(v.x), u1 = __float_as_uint(v.y);
  const uint u2 = __float_as_uint(v.z), u3 = __float_as_uint(v.w);
  const uint h01 = (u0 >> 16) | (u1 & 0xffff0000u);
  const uint h23 = (u2 >> 16) | (u3 & 0xffff0000u);
  const float l0 = v.x - __uint_as_float(u0 & 0xffff0000u);
  const float l1 = v.y - __uint_as_float(u1 & 0xffff0000u);
  const float l2 = v.z - __uint_as_float(u2 & 0xffff0000u);
  const float l3 = v.w - __uint_as_float(u3 & 0xffff0000u);
  const uint l01 = bf16rn(l0) | (bf16rn(l1) << 16);
  const uint l23 = bf16rn(l2) | (bf16rn(l3) << 16);
  ushort* dh = dst + (size_t)blockIdx.y * 524288;
  ((uint2*)dh)[i] = make_uint2(h01, h23);
  ((uint2*)(dh + 262144))[i] = make_uint2(l01, l23);
}

// ---------------------------------------------------------------------------
// Split-bf16 MFMA GEMM (NT): Co[M,512] = A[M,512] @ W[512,512]^T (+bias)(+Add)
// with optional ReLU6 clip before Add. A fp32 -> hi/lo bf16 staged in LDS;
// W pre-split (Wh/Wl bf16). 3 MFMA terms: Ah*Bh + Al*Bh + Ah*Bl.
// Tile 128x128, BK=64 real K, 256 thr = 4 waves (2x2 of 64x64), 16x16x32 MFMA.
// LDS rows are 128B with XOR swizzle byte^=(row&7)<<4 (conflict-free b128).
// grid: (4 n-tiles, 576 m-tiles) -- x fastest shares the A panel in L2.
// ---------------------------------------------------------------------------
__global__ __launch_bounds__(256) void gemm_mfma_k(
    const float* __restrict__ A, const ushort* __restrict__ Wh,
    const ushort* __restrict__ Wl, const float* __restrict__ Add,
    const float* __restrict__ bias, float* __restrict__ Co, const int clip) {
  __shared__ __align__(16) ushort lA[16384];  // hi [128][64] at 0, lo at +16384B
  __shared__ __align__(16) ushort lB[16384];
  const int t = threadIdx.x;
  const int n0 = blockIdx.x * 128;
  const int m0 = blockIdx.y * 128;
  const int lane = t & 63;
  const int w = t >> 6;
  const int wr = (w >> 1) * 64;
  const int wc = (w & 1) * 64;
  const int ln15 = lane & 15;
  const int lk = lane >> 4;  // 0..3

  f32x4 acc[4][4];
#pragma unroll
  for (int i = 0; i < 4; ++i)
#pragma unroll
    for (int j = 0; j < 4; ++j) acc[i][j] = (f32x4){0.f, 0.f, 0.f, 0.f};

  for (int k0 = 0; k0 < 512; k0 += 64) {
    // ---- stage A: 128 rows x 64 k fp32 -> hi/lo bf16 (swizzled) ----
#pragma unroll
    for (int i = 0; i < 8; ++i) {
      const int idx = t + i * 256;        // < 2048
      const int row = idx >> 4;           // 0..127
      const int kq = (idx & 15) << 2;     // 0..60
      const float4 v = *(const float4*)&A[(size_t)(m0 + row) * 512 + k0 + kq];
      const uint u0 = __float_as_uint(v.x), u1 = __float_as_uint(v.y);
      const uint u2 = __float_as_uint(v.z), u3 = __float_as_uint(v.w);
      const uint h01 = (u0 >> 16) | (u1 & 0xffff0000u);
      const uint h23 = (u2 >> 16) | (u3 & 0xffff0000u);
      const float f0 = v.x - __uint_as_float(u0 & 0xffff0000u);
      const float f1 = v.y - __uint_as_float(u1 & 0xffff0000u);
      const float f2 = v.z - __uint_as_float(u2 & 0xffff0000u);
      const float f3 = v.w - __uint_as_float(u3 & 0xffff0000u);
      const uint l01 = bf16rn(f0) | (bf16rn(f1) << 16);
      const uint l23 = bf16rn(f2) | (bf16rn(f3) << 16);
      const int c = (kq << 1) ^ ((row & 7) << 4);
      char* p = (char*)lA + row * 128 + c;
      *(uint2*)p = make_uint2(h01, h23);
      *(uint2*)(p + 16384) = make_uint2(l01, l23);
    }
    // ---- stage B: 128 rows x 64 k bf16 hi/lo from global (swizzled) ----
#pragma unroll
    for (int i = 0; i < 4; ++i) {
      const int idx = t + i * 256;        // < 1024
      const int row = idx >> 3;           // 0..127
      const int kq = (idx & 7) << 3;      // 0..56
      const size_t g = (size_t)(n0 + row) * 512 + k0 + kq;
      const int c = (kq << 1) ^ ((row & 7) << 4);
      *(uint4*)((char*)lB + row * 128 + c) = *(const uint4*)&Wh[g];
      *(uint4*)((char*)lB + 16384 + row * 128 + c) = *(const uint4*)&Wl[g];
    }
    __syncthreads();
#pragma unroll
    for (int ks = 0; ks < 2; ++ks) {
      bf16x8 ah[4], al[4], bh[4], bl[4];
      const int kb = ks * 64 + lk * 16;   // byte offset of this lane's 8 bf16
#pragma unroll
      for (int f = 0; f < 4; ++f) {
        const int ra = wr + f * 16 + ln15;
        const int ca = kb ^ ((ra & 7) << 4);
        ah[f] = *(const bf16x8*)((const char*)lA + ra * 128 + ca);
        al[f] = *(const bf16x8*)((const char*)lA + 16384 + ra * 128 + ca);
        const int rb = wc + f * 16 + ln15;
        const int cb = kb ^ ((rb & 7) << 4);
        bh[f] = *(const bf16x8*)((const char*)lB + rb * 128 + cb);
        bl[f] = *(const bf16x8*)((const char*)lB + 16384 + rb * 128 + cb);
      }
#pragma unroll
      for (int fm = 0; fm < 4; ++fm)
#pragma unroll
        for (int fn = 0; fn < 4; ++fn) {
          acc[fm][fn] = __builtin_amdgcn_mfma_f32_16x16x32_bf16(
              ah[fm], bh[fn], acc[fm][fn], 0, 0, 0);
          acc[fm][fn] = __builtin_amdgcn_mfma_f32_16x16x32_bf16(
              al[fm], bh[fn], acc[fm][fn], 0, 0, 0);
          acc[fm][fn] = __builtin_amdgcn_mfma_f32_16x16x32_bf16(
              ah[fm], bl[fn], acc[fm][fn], 0, 0, 0);
        }
    }
    __syncthreads();
  }

  // ---- epilogue: C/D map col=lane&15, row=(lane>>4)*4+j (m89/m91) ----
#pragma unroll
  for (int fm = 0; fm < 4; ++fm) {
#pragma unroll
    for (int j = 0; j < 4; ++j) {
      const int row = m0 + wr + fm * 16 + lk * 4 + j;
#pragma unroll
      for (int fn = 0; fn < 4; ++fn) {
        const int col = n0 + wc + fn * 16 + ln15;
        float r = acc[fm][fn][j];
        if (clip) r = fminf(fmaxf(r, 0.f), 6.f);
        if (bias) r += bias[col];
        if (Add) r += Add[(size_t)row * 512 + col];
        Co[(size_t)row * 512 + col] = r;
      }
    }
  }
}

// ---------------------------------------------------------------------------
// Attention: per (n, head) block. Q,K,V token-major [73728, 512].
// scores = (Qh @ Kh^T)/8, softmax rows, O = P @ Vh. T=96, dh=64.
// ---------------------------------------------------------------------------
__global__ __launch_bounds__(256) void attn_kernel(const float* __restrict__ Q,
                                                   const float* __restrict__ Km,
                                                   const float* __restrict__ Vm,
                                                   float* __restrict__ O) {
  __shared__ float sm[2 * 96 * 66];  // qs | ks ; later reused for scores (96*97)
  float* qs = sm;
  float* ks = sm + 96 * 66;
  float* ss = sm;
  const int n = blockIdx.x;
  const int hd = blockIdx.y;
  const int t = threadIdx.x;
  const size_t base = (size_t)n * 96 * 512 + (size_t)hd * 64;

  for (int f = t; f < 3072; f += 256) {
    const int row = f >> 5;
    const int d2 = (f & 31) << 1;
    const size_t g = base + (size_t)row * 512 + d2;
    *(float2*)&qs[row * 66 + d2] = *(const float2*)&Q[g];
    *(float2*)&ks[row * 66 + d2] = *(const float2*)&Km[g];
  }
  __syncthreads();

  float sc[12][3];
  {
    const int tx = t & 31, ty = t >> 5;
#pragma unroll
    for (int ii = 0; ii < 12; ++ii) { sc[ii][0] = 0.f; sc[ii][1] = 0.f; sc[ii][2] = 0.f; }
#pragma unroll 8
    for (int d = 0; d < 64; d += 2) {
      const float2 k0 = *(const float2*)&ks[tx * 66 + d];
      const float2 k1 = *(const float2*)&ks[(tx + 32) * 66 + d];
      const float2 k2 = *(const float2*)&ks[(tx + 64) * 66 + d];
#pragma unroll
      for (int ii = 0; ii < 12; ++ii) {
        const float2 qv = *(const float2*)&qs[(ty + 8 * ii) * 66 + d];
        sc[ii][0] += qv.x * k0.x + qv.y * k0.y;
        sc[ii][1] += qv.x * k1.x + qv.y * k1.y;
        sc[ii][2] += qv.x * k2.x + qv.y * k2.y;
      }
    }
  }
  __syncthreads();
  {
    const int tx = t & 31, ty = t >> 5;
#pragma unroll
    for (int ii = 0; ii < 12; ++ii) {
      ss[(ty + 8 * ii) * 97 + tx] = sc[ii][0] * 0.125f;
      ss[(ty + 8 * ii) * 97 + tx + 32] = sc[ii][1] * 0.125f;
      ss[(ty + 8 * ii) * 97 + tx + 64] = sc[ii][2] * 0.125f;
    }
  }
  __syncthreads();

  if (t < 96) {
    float mx = -3.4e38f;
    for (int j = 0; j < 96; ++j) mx = fmaxf(mx, ss[t * 97 + j]);
    float sum = 0.f;
    for (int j = 0; j < 96; ++j) {
      const float e = __expf(ss[t * 97 + j] - mx);
      ss[t * 97 + j] = e;
      sum += e;
    }
    const float inv = 1.f / sum;
    for (int j = 0; j < 96; ++j) ss[t * 97 + j] *= inv;
  }
  __syncthreads();

  {
    const int d = (t & 31) << 1;
    const int ib = t >> 5;  // 0..7
    float oc[12][2];
#pragma unroll
    for (int ii = 0; ii < 12; ++ii) { oc[ii][0] = 0.f; oc[ii][1] = 0.f; }
#pragma unroll 4
    for (int j = 0; j < 96; ++j) {
      const float2 pv = *(const float2*)&Vm[base + (size_t)j * 512 + d];
#pragma unroll
      for (int ii = 0; ii < 12; ++ii) {
        const float p = ss[(ib + 8 * ii) * 97 + j];
        oc[ii][0] += p * pv.x;
        oc[ii][1] += p * pv.y;
      }
    }
#pragma unroll
    for (int ii = 0; ii < 12; ++ii)
      *(float2*)&O[base + (size_t)(ib + 8 * ii) * 512 + d] = *(float2*)&oc[ii][0];
  }
}

// ---------------------------------------------------------------------------
// Depthwise 3x3 (SAME) + BatchNorm(eval): y in bchw layout
// ---------------------------------------------------------------------------
__global__ __launch_bounds__(256) void dwconv_bn_k(const float* __restrict__ x,
                                                   const float* __restrict__ w9,
                                                   const float* __restrict__ g,
                                                   const float* __restrict__ bta,
                                                   const float* __restrict__ mu,
                                                   const float* __restrict__ var,
                                                   float* __restrict__ y) {
  const int idx = blockIdx.x * 256 + threadIdx.x;  // < 37748736
  const int wq = idx % 96;
  const int r1 = idx / 96;
  const int hq = r1 % 96;
  const int c = (r1 / 96) & 511;
  const int bq = idx / 4718592;
  const float* xb = x + ((size_t)bq * NC + c) * HWSZ;
  const float* wc = w9 + c * 9;
  float acc = 0.f;
#pragma unroll
  for (int di = -1; di <= 1; ++di) {
    const int h2 = hq + di;
    if (h2 < 0 || h2 > 95) continue;
#pragma unroll
    for (int dj = -1; dj <= 1; ++dj) {
      const int w2 = wq + dj;
      if (w2 < 0 || w2 > 95) continue;
      acc += xb[h2 * 96 + w2] * wc[(di + 1) * 3 + (dj + 1)];
    }
  }
  const float scl = g[c] / sqrtf(var[c] + 1e-5f);
  y[idx] = (acc - mu[c]) * scl + bta[c];
}

// ---------------------------------------------------------------------------
// Schedule (4 ws buffers of 151MB; weight hi/lo splits live in d_out until the
// final transpose overwrites it):
//  w0: Xt(1-5r) -> xp(7w,8r) -> CR(10w,13r)
//  w1: K(2w,4r) -> KV2(5w,9r) -> YdwTok(12w,13r)
//  w2: V(3w,4r) -> O1(6w,7r) -> A2(9w,10r) -> OutTok(13w,14r)
//  w3: A1(4w,6r) -> Q2(8w,9r) -> Ydw bchw(11w,12r)
// ---------------------------------------------------------------------------
extern "C" void kernel_launch(void* const* d_in, const int* in_sizes, int n_in,
                              void* d_out, int out_size, void* d_ws, size_t ws_size,
                              hipStream_t stream) {
  const float* x   = (const float*)d_in[0];
  const float* Wk  = (const float*)d_in[1];
  const float* Wv  = (const float*)d_in[2];
  const float* Wo  = (const float*)d_in[3];
  const float* cWq = (const float*)d_in[4];
  const float* cbq = (const float*)d_in[5];
  const float* cWv = (const float*)d_in[6];
  const float* cWo = (const float*)d_in[7];
  const float* dw  = (const float*)d_in[8];
  const float* bng = (const float*)d_in[9];
  const float* bnb = (const float*)d_in[10];
  const float* bnm = (const float*)d_in[11];
  const float* bnv = (const float*)d_in[12];
  const float* pw  = (const float*)d_in[13];
  float* out = (float*)d_out;
  float* ws = (float*)d_ws;

  const size_t SZ = (size_t)MTOK * NC;
  float* w0 = ws;
  float* w1 = ws + SZ;
  float* w2 = ws + 2 * SZ;
  float* w3 = ws + 3 * SZ;

  // weight hi/lo area: 7 matrices x 1MB, parked in d_out (dead until step 14)
  ushort* wx = (ushort*)d_out;
  const size_t WME = 524288;  // ushorts per matrix (hi+lo)
#define WH(i) (wx + (i) * WME)
#define WL(i) (wx + (i) * WME + 262144)

  const dim3 tb(32, 8);
  const dim3 tg(48, 96, 8);       // transposes
  const dim3 gg(4, 576);          // MFMA gemm: x = n-tile (A-panel L2 reuse)

  // 0. split weights to bf16 hi/lo:  0=Wk 1=Wv 2=Wo 3=cWq 4=cWv 5=cWo 6=pw
  wext_k<<<dim3(256, 7), 256, 0, stream>>>(Wk, Wv, Wo, cWq, cWv, cWo, pw, wx);
  // 1. vqk tokens: w0 = Xt
  bchw_to_tok_k<<<tg, tb, 0, stream>>>(x, w0);
  // 2. K = Xt@Wk^T + Xt -> w1
  gemm_mfma_k<<<gg, 256, 0, stream>>>(w0, WH(0), WL(0), w0, nullptr, w1, 0);
  // 3. V = Xt@Wv^T -> w2
  gemm_mfma_k<<<gg, 256, 0, stream>>>(w0, WH(1), WL(1), nullptr, nullptr, w2, 0);
  // 4. MSA attention (q = Xt) -> w3 = A1
  attn_kernel<<<dim3(768, 8), 256, 0, stream>>>(w0, w1, w2, w3);
  // 5. KV2 = Xt@cWv^T -> w1  (K dead; Xt last read here)
  gemm_mfma_k<<<gg, 256, 0, stream>>>(w0, WH(4), WL(4), nullptr, nullptr, w1, 0);
  // 6. O1 = A1@Wo^T -> w2  (V dead)
  gemm_mfma_k<<<gg, 256, 0, stream>>>(w3, WH(2), WL(2), nullptr, nullptr, w2, 0);
  // 7. odd reshape: xp[b,c,h,w] = O1 tokens -> w0  (Xt dead)
  tok_to_bchw_k<<<tg, tb, 0, stream>>>(w2, w0);
  // 8. Q2 = xp_flat@cWq^T + bq -> w3  (A1 dead)
  gemm_mfma_k<<<gg, 256, 0, stream>>>(w0, WH(3), WL(3), nullptr, cbq, w3, 0);
  // 9. Cross attention (q=Q2, k=v=KV2) -> w2  (O1 dead)
  attn_kernel<<<dim3(768, 8), 256, 0, stream>>>(w3, w1, w1, w2);
  // 10. CR = A2@cWo^T -> w0  (xp dead)
  gemm_mfma_k<<<gg, 256, 0, stream>>>(w2, WH(5), WL(5), nullptr, nullptr, w0, 0);
  // 11. depthwise conv + BN -> w3 bchw  (Q2 dead)
  dwconv_bn_k<<<147456, 256, 0, stream>>>(x, dw, bng, bnb, bnm, bnv, w3);
  // 12. Ydw tokens -> w1  (KV2 dead)
  bchw_to_tok_k<<<tg, tb, 0, stream>>>(w3, w1);
  // 13. OutTok = clip(YdwTok@pw^T) + CR -> w2  (A2 dead)
  gemm_mfma_k<<<gg, 256, 0, stream>>>(w1, WH(6), WL(6), w0, nullptr, w2, 1);
  // 14. OutTok -> bchw d_out  (weight area dead)
  tok_to_bchw_k<<<tg, tb, 0, stream>>>(w2, out);
}

// Round 5
// 3332.050 us; speedup vs baseline: 1.3806x; 1.0884x over previous
//
#include <hip/hip_runtime.h>
#include <hip/hip_bf16.h>
#include <cstddef>

// Problem constants: B=8, C=512, H=96, W=96, NHEADS=8, dh=64.
// Token view: M = B*W*H = 73728 tokens, token m = bb*9216 + ww*96 + hh.
#define NB 8
#define NC 512
#define NH 96
#define NW 96
#define HWSZ 9216          // 96*96
#define CHW 4718592ull     // 512*96*96
#define MTOK 73728         // 8*96*96

typedef __attribute__((ext_vector_type(8))) short bf16x8;
typedef __attribute__((ext_vector_type(4))) float f32x4;
typedef unsigned int uint;
typedef unsigned short ushort;

__device__ inline uint bf16rn(float f) {
  uint v = __float_as_uint(f);
  return (v + 0x7fffu + ((v >> 16) & 1u)) >> 16;  // round-to-nearest-even bf16
}

// fp32x4 -> (hi trunc-bf16 x4 packed, lo rn-bf16(residual) x4 packed)
__device__ inline void split4(const float4 v, uint2& hi, uint2& lo) {
  const uint u0 = __float_as_uint(v.x), u1 = __float_as_uint(v.y);
  const uint u2 = __float_as_uint(v.z), u3 = __float_as_uint(v.w);
  hi = make_uint2((u0 >> 16) | (u1 & 0xffff0000u),
                  (u2 >> 16) | (u3 & 0xffff0000u));
  const float f0 = v.x - __uint_as_float(u0 & 0xffff0000u);
  const float f1 = v.y - __uint_as_float(u1 & 0xffff0000u);
  const float f2 = v.z - __uint_as_float(u2 & 0xffff0000u);
  const float f3 = v.w - __uint_as_float(u3 & 0xffff0000u);
  lo = make_uint2(bf16rn(f0) | (bf16rn(f1) << 16),
                  bf16rn(f2) | (bf16rn(f3) << 16));
}

// ---------------------------------------------------------------------------
// Transpose: x[b,c,h,w] -> T[m, c]  (m = b*9216 + w*96 + h)
// ---------------------------------------------------------------------------
__global__ __launch_bounds__(256) void bchw_to_tok_k(const float* __restrict__ x,
                                                     float* __restrict__ T) {
  __shared__ float s[32][33];
  const int tx = threadIdx.x;       // 0..31
  const int ty = threadIdx.y;       // 0..7
  const int cc0 = (blockIdx.x / 3) * 32;
  const int ww0 = (blockIdx.x % 3) * 32;
  const int hh = blockIdx.y;
  const int bb = blockIdx.z;
#pragma unroll
  for (int i = 0; i < 4; ++i) {
    s[ty + 8 * i][tx] =
        x[(((size_t)bb * NC + cc0 + ty + 8 * i) * NH + hh) * NW + ww0 + tx];
  }
  __syncthreads();
#pragma unroll
  for (int i = 0; i < 4; ++i) {
    T[((size_t)bb * HWSZ + (size_t)(ww0 + ty + 8 * i) * NH + hh) * NC + cc0 + tx] =
        s[tx][ty + 8 * i];
  }
}

// Inverse: Y[b,c,h,w] = T[m, c]
__global__ __launch_bounds__(256) void tok_to_bchw_k(const float* __restrict__ T,
                                                     float* __restrict__ Y) {
  __shared__ float s[32][33];
  const int tx = threadIdx.x;
  const int ty = threadIdx.y;
  const int cc0 = (blockIdx.x / 3) * 32;
  const int ww0 = (blockIdx.x % 3) * 32;
  const int hh = blockIdx.y;
  const int bb = blockIdx.z;
#pragma unroll
  for (int i = 0; i < 4; ++i) {
    s[ty + 8 * i][tx] =
        T[((size_t)bb * HWSZ + (size_t)(ww0 + ty + 8 * i) * NH + hh) * NC + cc0 + tx];
  }
  __syncthreads();
#pragma unroll
  for (int i = 0; i < 4; ++i) {
    Y[(((size_t)bb * NC + cc0 + ty + 8 * i) * NH + hh) * NW + ww0 + tx] =
        s[tx][ty + 8 * i];
  }
}

// ---------------------------------------------------------------------------
// Weight split: W[512,512] fp32 -> Wh (trunc bf16) + Wl (rn bf16 of residual).
// dst layout: matrix mi -> hi at mi*524288, lo at mi*524288+262144 (ushorts).
// ---------------------------------------------------------------------------
__global__ __launch_bounds__(256) void wext_k(const float* __restrict__ W0,
                                              const float* __restrict__ W1,
                                              const float* __restrict__ W2,
                                              const float* __restrict__ W3,
                                              const float* __restrict__ W4,
                                              const float* __restrict__ W5,
                                              const float* __restrict__ W6,
                                              ushort* __restrict__ dst) {
  const float* srcs[7] = {W0, W1, W2, W3, W4, W5, W6};
  const float* s = srcs[blockIdx.y];
  const int i = blockIdx.x * 256 + threadIdx.x;  // < 65536 (float4 units)
  const float4 v = ((const float4*)s)[i];
  uint2 hi, lo;
  split4(v, hi, lo);
  ushort* dh = dst + (size_t)blockIdx.y * 524288;
  ((uint2*)dh)[i] = hi;
  ((uint2*)(dh + 262144))[i] = lo;
}

// ---------------------------------------------------------------------------
// Split-bf16 MFMA GEMM (NT): Co[M,512] = A[M,512] @ W[512,512]^T (+bias)(+Add)
// with optional ReLU6 clip before Add. A fp32 -> hi/lo bf16 staged in LDS;
// W pre-split (Wh/Wl bf16). 3 MFMA terms: Ah*Bh + Al*Bh + Ah*Bl.
// Tile 128x128, BK=64 real K, 256 thr = 4 waves (2x2 of 64x64), 16x16x32 MFMA.
// LDS rows are 128B with XOR swizzle byte^=(row&7)<<4 (conflict-free b128).
// grid: (4 n-tiles, 576 m-tiles) -- x fastest shares the A panel in L2.
// ---------------------------------------------------------------------------
__global__ __launch_bounds__(256) void gemm_mfma_k(
    const float* __restrict__ A, const ushort* __restrict__ Wh,
    const ushort* __restrict__ Wl, const float* __restrict__ Add,
    const float* __restrict__ bias, float* __restrict__ Co, const int clip) {
  __shared__ __align__(16) ushort lA[16384];  // hi [128][64] at 0, lo at +16384B
  __shared__ __align__(16) ushort lB[16384];
  const int t = threadIdx.x;
  const int n0 = blockIdx.x * 128;
  const int m0 = blockIdx.y * 128;
  const int lane = t & 63;
  const int w = t >> 6;
  const int wr = (w >> 1) * 64;
  const int wc = (w & 1) * 64;
  const int ln15 = lane & 15;
  const int lk = lane >> 4;  // 0..3

  f32x4 acc[4][4];
#pragma unroll
  for (int i = 0; i < 4; ++i)
#pragma unroll
    for (int j = 0; j < 4; ++j) acc[i][j] = (f32x4){0.f, 0.f, 0.f, 0.f};

  for (int k0 = 0; k0 < 512; k0 += 64) {
    // ---- stage A: 128 rows x 64 k fp32 -> hi/lo bf16 (swizzled) ----
#pragma unroll
    for (int i = 0; i < 8; ++i) {
      const int idx = t + i * 256;        // < 2048
      const int row = idx >> 4;           // 0..127
      const int kq = (idx & 15) << 2;     // 0..60
      const float4 v = *(const float4*)&A[(size_t)(m0 + row) * 512 + k0 + kq];
      uint2 hi, lo;
      split4(v, hi, lo);
      const int c = (kq << 1) ^ ((row & 7) << 4);
      char* p = (char*)lA + row * 128 + c;
      *(uint2*)p = hi;
      *(uint2*)(p + 16384) = lo;
    }
    // ---- stage B: 128 rows x 64 k bf16 hi/lo from global (swizzled) ----
#pragma unroll
    for (int i = 0; i < 4; ++i) {
      const int idx = t + i * 256;        // < 1024
      const int row = idx >> 3;           // 0..127
      const int kq = (idx & 7) << 3;      // 0..56
      const size_t g = (size_t)(n0 + row) * 512 + k0 + kq;
      const int c = (kq << 1) ^ ((row & 7) << 4);
      *(uint4*)((char*)lB + row * 128 + c) = *(const uint4*)&Wh[g];
      *(uint4*)((char*)lB + 16384 + row * 128 + c) = *(const uint4*)&Wl[g];
    }
    __syncthreads();
#pragma unroll
    for (int ks = 0; ks < 2; ++ks) {
      bf16x8 ah[4], al[4], bh[4], bl[4];
      const int kb = ks * 64 + lk * 16;   // byte offset of this lane's 8 bf16
#pragma unroll
      for (int f = 0; f < 4; ++f) {
        const int ra = wr + f * 16 + ln15;
        const int ca = kb ^ ((ra & 7) << 4);
        ah[f] = *(const bf16x8*)((const char*)lA + ra * 128 + ca);
        al[f] = *(const bf16x8*)((const char*)lA + 16384 + ra * 128 + ca);
        const int rb = wc + f * 16 + ln15;
        const int cb = kb ^ ((rb & 7) << 4);
        bh[f] = *(const bf16x8*)((const char*)lB + rb * 128 + cb);
        bl[f] = *(const bf16x8*)((const char*)lB + 16384 + rb * 128 + cb);
      }
#pragma unroll
      for (int fm = 0; fm < 4; ++fm)
#pragma unroll
        for (int fn = 0; fn < 4; ++fn) {
          acc[fm][fn] = __builtin_amdgcn_mfma_f32_16x16x32_bf16(
              ah[fm], bh[fn], acc[fm][fn], 0, 0, 0);
          acc[fm][fn] = __builtin_amdgcn_mfma_f32_16x16x32_bf16(
              al[fm], bh[fn], acc[fm][fn], 0, 0, 0);
          acc[fm][fn] = __builtin_amdgcn_mfma_f32_16x16x32_bf16(
              ah[fm], bl[fn], acc[fm][fn], 0, 0, 0);
        }
    }
    __syncthreads();
  }

  // ---- epilogue: C/D map col=lane&15, row=(lane>>4)*4+j (m89/m91) ----
#pragma unroll
  for (int fm = 0; fm < 4; ++fm) {
#pragma unroll
    for (int j = 0; j < 4; ++j) {
      const int row = m0 + wr + fm * 16 + lk * 4 + j;
#pragma unroll
      for (int fn = 0; fn < 4; ++fn) {
        const int col = n0 + wc + fn * 16 + ln15;
        float r = acc[fm][fn][j];
        if (clip) r = fminf(fmaxf(r, 0.f), 6.f);
        if (bias) r += bias[col];
        if (Add) r += Add[(size_t)row * 512 + col];
        Co[(size_t)row * 512 + col] = r;
      }
    }
  }
}

// ---------------------------------------------------------------------------
// MFMA attention: one block per (n, head). Q,K,V token-major fp32 [73728,512].
// scores = (Qh@Kh^T)/8 via split-bf16 3-term MFMA; pair-per-row softmax with
// in-place P->bf16 hi/lo conversion; O = P@V via MFMA with V^T staged hi/lo
// in two 32-d halves. LDS = exactly 64KB.
//   [0,12288)  qh [96][64]bf16, row stride 128B, byte^=(row&7)<<4
//   [12288..)  ql ; [24576..) kh ; [36864..49152) kl
//   after QK:  ss fp32 [96] rows, stride 512B: scores at +[0,384)
//              then P:  hi at +(kb^sw) kb in [0,192), lo at +256+(kb^sw)
//   [49152,57344) vt_hi [32][96]bf16 stride 256B ; [57344,65536) vt_lo
// ---------------------------------------------------------------------------
__global__ __launch_bounds__(256) void attn_mfma_k(const float* __restrict__ Q,
                                                   const float* __restrict__ Km,
                                                   const float* __restrict__ Vm,
                                                   float* __restrict__ O) {
  __shared__ __align__(16) char smem[65536];
  const int n = blockIdx.x;
  const int hd = blockIdx.y;
  const int t = threadIdx.x;
  const size_t abase = (size_t)n * 96 * 512 + (size_t)hd * 64;
  const int lane = t & 63;
  const int w = t >> 6;
  const int ln15 = lane & 15;
  const int g = lane >> 4;        // 0..3
  const int wr = (w >> 1) * 48;   // wave row base (48 rows)
  const int wcs = (w & 1) * 48;   // wave col base for scores
  const int wcp = (w & 1) * 16;   // wave col base within a 32-d PV half

  // ---- phase 1: stage Q,K hi/lo + V^T half 0 ----
#pragma unroll
  for (int i = 0; i < 6; ++i) {
    const int idx = t + i * 256;          // < 1536
    const int row = idx >> 4;             // 0..95
    const int kq = (idx & 15) << 2;       // 0..60
    const int c = (kq << 1) ^ ((row & 7) << 4);
    uint2 hi, lo;
    float4 v = *(const float4*)&Q[abase + (size_t)row * 512 + kq];
    split4(v, hi, lo);
    *(uint2*)(smem + row * 128 + c) = hi;
    *(uint2*)(smem + 12288 + row * 128 + c) = lo;
    v = *(const float4*)&Km[abase + (size_t)row * 512 + kq];
    split4(v, hi, lo);
    *(uint2*)(smem + 24576 + row * 128 + c) = hi;
    *(uint2*)(smem + 36864 + row * 128 + c) = lo;
  }
  // V^T half 0 (d 0..31): vt[d][j]
#pragma unroll
  for (int i = 0; i < 6; ++i) {
    const int j = (t >> 4) + i * 16;      // 0..95
    const int dl = (t & 15) << 1;         // 0,2,..,30
    const float2 v = *(const float2*)&Vm[abase + (size_t)j * 512 + dl];
    const uint u0 = __float_as_uint(v.x), u1 = __float_as_uint(v.y);
    const ushort h0 = (ushort)(u0 >> 16), h1 = (ushort)(u1 >> 16);
    const ushort l0 = (ushort)bf16rn(v.x - __uint_as_float(u0 & 0xffff0000u));
    const ushort l1 = (ushort)bf16rn(v.y - __uint_as_float(u1 & 0xffff0000u));
    const int c0 = (j << 1) ^ ((dl & 7) << 4);
    const int c1 = (j << 1) ^ (((dl + 1) & 7) << 4);
    *(ushort*)(smem + 49152 + dl * 256 + c0) = h0;
    *(ushort*)(smem + 57344 + dl * 256 + c0) = l0;
    *(ushort*)(smem + 49152 + (dl + 1) * 256 + c1) = h1;
    *(ushort*)(smem + 57344 + (dl + 1) * 256 + c1) = l1;
  }
  __syncthreads();

  // ---- phase 2: scores = Q @ K^T (3-term split), 48x48 per wave ----
  f32x4 acc[3][3];
#pragma unroll
  for (int i = 0; i < 3; ++i)
#pragma unroll
    for (int j = 0; j < 3; ++j) acc[i][j] = (f32x4){0.f, 0.f, 0.f, 0.f};
#pragma unroll
  for (int ks = 0; ks < 2; ++ks) {
    const int kb = ks * 64 + g * 16;
    bf16x8 ah[3], al[3], bh[3], bl[3];
#pragma unroll
    for (int f = 0; f < 3; ++f) {
      const int ra = wr + f * 16 + ln15;
      const int ca = kb ^ ((ra & 7) << 4);
      ah[f] = *(const bf16x8*)(smem + ra * 128 + ca);
      al[f] = *(const bf16x8*)(smem + 12288 + ra * 128 + ca);
      const int rb = wcs + f * 16 + ln15;
      const int cb = kb ^ ((rb & 7) << 4);
      bh[f] = *(const bf16x8*)(smem + 24576 + rb * 128 + cb);
      bl[f] = *(const bf16x8*)(smem + 36864 + rb * 128 + cb);
    }
#pragma unroll
    for (int fm = 0; fm < 3; ++fm)
#pragma unroll
      for (int fn = 0; fn < 3; ++fn) {
        acc[fm][fn] = __builtin_amdgcn_mfma_f32_16x16x32_bf16(
            ah[fm], bh[fn], acc[fm][fn], 0, 0, 0);
        acc[fm][fn] = __builtin_amdgcn_mfma_f32_16x16x32_bf16(
            al[fm], bh[fn], acc[fm][fn], 0, 0, 0);
        acc[fm][fn] = __builtin_amdgcn_mfma_f32_16x16x32_bf16(
            ah[fm], bl[fn], acc[fm][fn], 0, 0, 0);
      }
  }
  __syncthreads();  // Q/K LDS dead; region becomes ss/P

  // ---- phase 3: scaled scores -> ss fp32 (row stride 512B) ----
#pragma unroll
  for (int fm = 0; fm < 3; ++fm)
#pragma unroll
    for (int j = 0; j < 4; ++j) {
      const int row = wr + fm * 16 + g * 4 + j;
#pragma unroll
      for (int fn = 0; fn < 3; ++fn) {
        const int col = wcs + fn * 16 + ln15;
        *(float*)(smem + row * 512 + col * 4) = acc[fm][fn][j] * 0.125f;
      }
    }
  __syncthreads();

  // ---- phase 4: softmax (2 threads/row, same wave) + in-place P hi/lo ----
  if (t < 192) {
    const int row = t >> 1;
    const int hf = t & 1;
    float v[48];
    const char* rp = smem + row * 512 + hf * 192;
#pragma unroll
    for (int i = 0; i < 12; ++i) *(float4*)&v[i * 4] = *(const float4*)(rp + i * 16);
    float mx = v[0];
#pragma unroll
    for (int i = 1; i < 48; ++i) mx = fmaxf(mx, v[i]);
    mx = fmaxf(mx, __shfl_xor(mx, 1));
    float s = 0.f;
#pragma unroll
    for (int i = 0; i < 48; ++i) { v[i] = __expf(v[i] - mx); s += v[i]; }
    s += __shfl_xor(s, 1);
    const float inv = 1.f / s;
    const int sw = (row & 7) << 4;
#pragma unroll
    for (int c = 0; c < 6; ++c) {
      uint hw[4], lw[4];
#pragma unroll
      for (int q = 0; q < 4; ++q) {
        const float p0 = v[c * 8 + q * 2] * inv;
        const float p1 = v[c * 8 + q * 2 + 1] * inv;
        const uint u0 = __float_as_uint(p0), u1 = __float_as_uint(p1);
        hw[q] = (u0 >> 16) | (u1 & 0xffff0000u);
        const float l0 = p0 - __uint_as_float(u0 & 0xffff0000u);
        const float l1 = p1 - __uint_as_float(u1 & 0xffff0000u);
        lw[q] = bf16rn(l0) | (bf16rn(l1) << 16);
      }
      const int kb = hf * 96 + c * 16;
      *(uint4*)(smem + row * 512 + (kb ^ sw)) =
          make_uint4(hw[0], hw[1], hw[2], hw[3]);
      *(uint4*)(smem + row * 512 + 256 + (kb ^ sw)) =
          make_uint4(lw[0], lw[1], lw[2], lw[3]);
    }
  }
  __syncthreads();

  // ---- phase 5/6: O = P @ V in two 32-d halves ----
  for (int h = 0; h < 2; ++h) {
    if (h == 1) {
      __syncthreads();  // PV half-0 vt reads done
#pragma unroll
      for (int i = 0; i < 6; ++i) {
        const int j = (t >> 4) + i * 16;
        const int dl = (t & 15) << 1;
        const float2 v = *(const float2*)&Vm[abase + (size_t)j * 512 + 32 + dl];
        const uint u0 = __float_as_uint(v.x), u1 = __float_as_uint(v.y);
        const ushort h0 = (ushort)(u0 >> 16), h1 = (ushort)(u1 >> 16);
        const ushort l0 = (ushort)bf16rn(v.x - __uint_as_float(u0 & 0xffff0000u));
        const ushort l1 = (ushort)bf16rn(v.y - __uint_as_float(u1 & 0xffff0000u));
        const int c0 = (j << 1) ^ ((dl & 7) << 4);
        const int c1 = (j << 1) ^ (((dl + 1) & 7) << 4);
        *(ushort*)(smem + 49152 + dl * 256 + c0) = h0;
        *(ushort*)(smem + 57344 + dl * 256 + c0) = l0;
        *(ushort*)(smem + 49152 + (dl + 1) * 256 + c1) = h1;
        *(ushort*)(smem + 57344 + (dl + 1) * 256 + c1) = l1;
      }
      __syncthreads();
    }
    f32x4 po[3];
#pragma unroll
    for (int i = 0; i < 3; ++i) po[i] = (f32x4){0.f, 0.f, 0.f, 0.f};
#pragma unroll
    for (int ks = 0; ks < 3; ++ks) {
      const int kb = ks * 64 + g * 16;
      bf16x8 ph[3], pl[3];
#pragma unroll
      for (int fm = 0; fm < 3; ++fm) {
        const int row = wr + fm * 16 + ln15;
        const int c = kb ^ ((row & 7) << 4);
        ph[fm] = *(const bf16x8*)(smem + row * 512 + c);
        pl[fm] = *(const bf16x8*)(smem + row * 512 + 256 + c);
      }
      const int dr = wcp + ln15;
      const int cb = kb ^ ((dr & 7) << 4);
      const bf16x8 vh = *(const bf16x8*)(smem + 49152 + dr * 256 + cb);
      const bf16x8 vl = *(const bf16x8*)(smem + 57344 + dr * 256 + cb);
#pragma unroll
      for (int fm = 0; fm < 3; ++fm) {
        po[fm] = __builtin_amdgcn_mfma_f32_16x16x32_bf16(ph[fm], vh, po[fm], 0, 0, 0);
        po[fm] = __builtin_amdgcn_mfma_f32_16x16x32_bf16(pl[fm], vh, po[fm], 0, 0, 0);
        po[fm] = __builtin_amdgcn_mfma_f32_16x16x32_bf16(ph[fm], vl, po[fm], 0, 0, 0);
      }
    }
    const int d = h * 32 + wcp + ln15;
#pragma unroll
    for (int fm = 0; fm < 3; ++fm)
#pragma unroll
      for (int j = 0; j < 4; ++j) {
        const int row = wr + fm * 16 + g * 4 + j;
        O[abase + (size_t)row * 512 + d] = po[fm][j];
      }
  }
}

// ---------------------------------------------------------------------------
// Depthwise 3x3 (SAME) + BatchNorm(eval): y in bchw layout
// ---------------------------------------------------------------------------
__global__ __launch_bounds__(256) void dwconv_bn_k(const float* __restrict__ x,
                                                   const float* __restrict__ w9,
                                                   const float* __restrict__ g,
                                                   const float* __restrict__ bta,
                                                   const float* __restrict__ mu,
                                                   const float* __restrict__ var,
                                                   float* __restrict__ y) {
  const int idx = blockIdx.x * 256 + threadIdx.x;  // < 37748736
  const int wq = idx % 96;
  const int r1 = idx / 96;
  const int hq = r1 % 96;
  const int c = (r1 / 96) & 511;
  const int bq = idx / 4718592;
  const float* xb = x + ((size_t)bq * NC + c) * HWSZ;
  const float* wc = w9 + c * 9;
  float acc = 0.f;
#pragma unroll
  for (int di = -1; di <= 1; ++di) {
    const int h2 = hq + di;
    if (h2 < 0 || h2 > 95) continue;
#pragma unroll
    for (int dj = -1; dj <= 1; ++dj) {
      const int w2 = wq + dj;
      if (w2 < 0 || w2 > 95) continue;
      acc += xb[h2 * 96 + w2] * wc[(di + 1) * 3 + (dj + 1)];
    }
  }
  const float scl = g[c] / sqrtf(var[c] + 1e-5f);
  y[idx] = (acc - mu[c]) * scl + bta[c];
}

// ---------------------------------------------------------------------------
// Schedule (4 ws buffers of 151MB; weight hi/lo splits live in d_out until the
// final transpose overwrites it):
//  w0: Xt(1-5r) -> xp(7w,8r) -> CR(10w,13r)
//  w1: K(2w,4r) -> KV2(5w,9r) -> YdwTok(12w,13r)
//  w2: V(3w,4r) -> O1(6w,7r) -> A2(9w,10r) -> OutTok(13w,14r)
//  w3: A1(4w,6r) -> Q2(8w,9r) -> Ydw bchw(11w,12r)
// ---------------------------------------------------------------------------
extern "C" void kernel_launch(void* const* d_in, const int* in_sizes, int n_in,
                              void* d_out, int out_size, void* d_ws, size_t ws_size,
                              hipStream_t stream) {
  const float* x   = (const float*)d_in[0];
  const float* Wk  = (const float*)d_in[1];
  const float* Wv  = (const float*)d_in[2];
  const float* Wo  = (const float*)d_in[3];
  const float* cWq = (const float*)d_in[4];
  const float* cbq = (const float*)d_in[5];
  const float* cWv = (const float*)d_in[6];
  const float* cWo = (const float*)d_in[7];
  const float* dw  = (const float*)d_in[8];
  const float* bng = (const float*)d_in[9];
  const float* bnb = (const float*)d_in[10];
  const float* bnm = (const float*)d_in[11];
  const float* bnv = (const float*)d_in[12];
  const float* pw  = (const float*)d_in[13];
  float* out = (float*)d_out;
  float* ws = (float*)d_ws;

  const size_t SZ = (size_t)MTOK * NC;
  float* w0 = ws;
  float* w1 = ws + SZ;
  float* w2 = ws + 2 * SZ;
  float* w3 = ws + 3 * SZ;

  // weight hi/lo area: 7 matrices x 1MB, parked in d_out (dead until step 14)
  ushort* wx = (ushort*)d_out;
  const size_t WME = 524288;  // ushorts per matrix (hi+lo)
#define WH(i) (wx + (i) * WME)
#define WL(i) (wx + (i) * WME + 262144)

  const dim3 tb(32, 8);
  const dim3 tg(48, 96, 8);       // transposes
  const dim3 gg(4, 576);          // MFMA gemm: x = n-tile (A-panel L2 reuse)

  // 0. split weights to bf16 hi/lo:  0=Wk 1=Wv 2=Wo 3=cWq 4=cWv 5=cWo 6=pw
  wext_k<<<dim3(256, 7), 256, 0, stream>>>(Wk, Wv, Wo, cWq, cWv, cWo, pw, wx);
  // 1. vqk tokens: w0 = Xt
  bchw_to_tok_k<<<tg, tb, 0, stream>>>(x, w0);
  // 2. K = Xt@Wk^T + Xt -> w1
  gemm_mfma_k<<<gg, 256, 0, stream>>>(w0, WH(0), WL(0), w0, nullptr, w1, 0);
  // 3. V = Xt@Wv^T -> w2
  gemm_mfma_k<<<gg, 256, 0, stream>>>(w0, WH(1), WL(1), nullptr, nullptr, w2, 0);
  // 4. MSA attention (q = Xt) -> w3 = A1
  attn_mfma_k<<<dim3(768, 8), 256, 0, stream>>>(w0, w1, w2, w3);
  // 5. KV2 = Xt@cWv^T -> w1  (K dead; Xt last read here)
  gemm_mfma_k<<<gg, 256, 0, stream>>>(w0, WH(4), WL(4), nullptr, nullptr, w1, 0);
  // 6. O1 = A1@Wo^T -> w2  (V dead)
  gemm_mfma_k<<<gg, 256, 0, stream>>>(w3, WH(2), WL(2), nullptr, nullptr, w2, 0);
  // 7. odd reshape: xp[b,c,h,w] = O1 tokens -> w0  (Xt dead)
  tok_to_bchw_k<<<tg, tb, 0, stream>>>(w2, w0);
  // 8. Q2 = xp_flat@cWq^T + bq -> w3  (A1 dead)
  gemm_mfma_k<<<gg, 256, 0, stream>>>(w0, WH(3), WL(3), nullptr, cbq, w3, 0);
  // 9. Cross attention (q=Q2, k=v=KV2) -> w2  (O1 dead)
  attn_mfma_k<<<dim3(768, 8), 256, 0, stream>>>(w3, w1, w1, w2);
  // 10. CR = A2@cWo^T -> w0  (xp dead)
  gemm_mfma_k<<<gg, 256, 0, stream>>>(w2, WH(5), WL(5), nullptr, nullptr, w0, 0);
  // 11. depthwise conv + BN -> w3 bchw  (Q2 dead)
  dwconv_bn_k<<<147456, 256, 0, stream>>>(x, dw, bng, bnb, bnm, bnv, w3);
  // 12. Ydw tokens -> w1  (KV2 dead)
  bchw_to_tok_k<<<tg, tb, 0, stream>>>(w3, w1);
  // 13. OutTok = clip(YdwTok@pw^T) + CR -> w2  (A2 dead)
  gemm_mfma_k<<<gg, 256, 0, stream>>>(w1, WH(6), WL(6), w0, nullptr, w2, 1);
  // 14. OutTok -> bchw d_out  (weight area dead)
  tok_to_bchw_k<<<tg, tb, 0, stream>>>(w2, out);
}

// Round 6
// 2658.847 us; speedup vs baseline: 1.7302x; 1.2532x over previous
//
#include <hip/hip_runtime.h>
#include <hip/hip_bf16.h>
#include <cstddef>

// Problem constants: B=8, C=512, H=96, W=96, NHEADS=8, dh=64.
// Token view: M = B*W*H = 73728 tokens, token m = bb*9216 + ww*96 + hh.
#define NB 8
#define NC 512
#define NH 96
#define NW 96
#define HWSZ 9216          // 96*96
#define CHW 4718592ull     // 512*96*96
#define MTOK 73728         // 8*96*96

typedef __attribute__((ext_vector_type(8))) short bf16x8;
typedef __attribute__((ext_vector_type(4))) float f32x4;
typedef unsigned int uint;
typedef unsigned short ushort;

__device__ inline uint bf16rn(float f) {
  uint v = __float_as_uint(f);
  return (v + 0x7fffu + ((v >> 16) & 1u)) >> 16;  // round-to-nearest-even bf16
}

// fp32x4 -> (hi trunc-bf16 x4 packed, lo rn-bf16(residual) x4 packed)
__device__ inline void split4(const float4 v, uint2& hi, uint2& lo) {
  const uint u0 = __float_as_uint(v.x), u1 = __float_as_uint(v.y);
  const uint u2 = __float_as_uint(v.z), u3 = __float_as_uint(v.w);
  hi = make_uint2((u0 >> 16) | (u1 & 0xffff0000u),
                  (u2 >> 16) | (u3 & 0xffff0000u));
  const float f0 = v.x - __uint_as_float(u0 & 0xffff0000u);
  const float f1 = v.y - __uint_as_float(u1 & 0xffff0000u);
  const float f2 = v.z - __uint_as_float(u2 & 0xffff0000u);
  const float f3 = v.w - __uint_as_float(u3 & 0xffff0000u);
  lo = make_uint2(bf16rn(f0) | (bf16rn(f1) << 16),
                  bf16rn(f2) | (bf16rn(f3) << 16));
}

// ---------------------------------------------------------------------------
// Transpose: x[b,c,h,w] -> T[m, c]  (m = b*9216 + w*96 + h)
// ---------------------------------------------------------------------------
__global__ __launch_bounds__(256) void bchw_to_tok_k(const float* __restrict__ x,
                                                     float* __restrict__ T) {
  __shared__ float s[32][33];
  const int tx = threadIdx.x;       // 0..31
  const int ty = threadIdx.y;       // 0..7
  const int cc0 = (blockIdx.x / 3) * 32;
  const int ww0 = (blockIdx.x % 3) * 32;
  const int hh = blockIdx.y;
  const int bb = blockIdx.z;
#pragma unroll
  for (int i = 0; i < 4; ++i) {
    s[ty + 8 * i][tx] =
        x[(((size_t)bb * NC + cc0 + ty + 8 * i) * NH + hh) * NW + ww0 + tx];
  }
  __syncthreads();
#pragma unroll
  for (int i = 0; i < 4; ++i) {
    T[((size_t)bb * HWSZ + (size_t)(ww0 + ty + 8 * i) * NH + hh) * NC + cc0 + tx] =
        s[tx][ty + 8 * i];
  }
}

// Inverse: Y[b,c,h,w] = T[m, c]
__global__ __launch_bounds__(256) void tok_to_bchw_k(const float* __restrict__ T,
                                                     float* __restrict__ Y) {
  __shared__ float s[32][33];
  const int tx = threadIdx.x;
  const int ty = threadIdx.y;
  const int cc0 = (blockIdx.x / 3) * 32;
  const int ww0 = (blockIdx.x % 3) * 32;
  const int hh = blockIdx.y;
  const int bb = blockIdx.z;
#pragma unroll
  for (int i = 0; i < 4; ++i) {
    s[ty + 8 * i][tx] =
        T[((size_t)bb * HWSZ + (size_t)(ww0 + ty + 8 * i) * NH + hh) * NC + cc0 + tx];
  }
  __syncthreads();
#pragma unroll
  for (int i = 0; i < 4; ++i) {
    Y[(((size_t)bb * NC + cc0 + ty + 8 * i) * NH + hh) * NW + ww0 + tx] =
        s[tx][ty + 8 * i];
  }
}

// ---------------------------------------------------------------------------
// Weight split: W[512,512] fp32 -> Wh (trunc bf16) + Wl (rn bf16 of residual).
// dst layout: matrix mi -> hi at mi*524288, lo at mi*524288+262144 (ushorts).
// ---------------------------------------------------------------------------
__global__ __launch_bounds__(256) void wext_k(const float* __restrict__ W0,
                                              const float* __restrict__ W1,
                                              const float* __restrict__ W2,
                                              const float* __restrict__ W3,
                                              const float* __restrict__ W4,
                                              const float* __restrict__ W5,
                                              const float* __restrict__ W6,
                                              ushort* __restrict__ dst) {
  const float* srcs[7] = {W0, W1, W2, W3, W4, W5, W6};
  const float* s = srcs[blockIdx.y];
  const int i = blockIdx.x * 256 + threadIdx.x;  // < 65536 (float4 units)
  const float4 v = ((const float4*)s)[i];
  uint2 hi, lo;
  split4(v, hi, lo);
  ushort* dh = dst + (size_t)blockIdx.y * 524288;
  ((uint2*)dh)[i] = hi;
  ((uint2*)(dh + 262144))[i] = lo;
}

// ---------------------------------------------------------------------------
// Split-bf16 MFMA GEMM (NT): Co[M,512] = A[M,512] @ W[512,512]^T (+bias)(+Add)
// with optional ReLU6 clip before Add. 3 MFMA terms: Ah*Bh + Al*Bh + Ah*Bl.
// Tile 128x128, BK=64, 256 thr = 4 waves (2x2 of 64x64), 16x16x32 MFMA.
// LDS rows 128B with XOR swizzle byte^=(row&7)<<4 (conflict-free b128).
//
// R6 changes vs R5 (diagnosis: latency/fetch-bound, MfmaUtil=VALU=10%,
// FETCH=373MB=2.5x A because same-A-panel blocks land on different XCDs):
//  (a) bijective XCD remap: f=bx+4*by; xcd=f&7; idx=f>>3;
//      panel=xcd*72+idx/4; n=idx&3  -> same-panel blocks share one XCD L2.
//  (b) T14 async-STAGE: regs->LDS, barrier, issue NEXT tile's global loads,
//      MFMA (loads in flight under compute), barrier.
// ---------------------------------------------------------------------------
__global__ __launch_bounds__(256) void gemm_mfma_k(
    const float* __restrict__ A, const ushort* __restrict__ Wh,
    const ushort* __restrict__ Wl, const float* __restrict__ Add,
    const float* __restrict__ bias, float* __restrict__ Co, const int clip) {
  __shared__ __align__(16) ushort lA[16384];  // hi [128][64] at 0, lo at +16384B
  __shared__ __align__(16) ushort lB[16384];
  const int t = threadIdx.x;
  // --- XCD-aware bijective remap (grid 4 x 576 = 2304 = 8 XCD x 288) ---
  const int f = blockIdx.x + (blockIdx.y << 2);
  const int xcd = f & 7;
  const int idx = f >> 3;               // 0..287
  const int m0 = (xcd * 72 + (idx >> 2)) * 128;
  const int n0 = (idx & 3) * 128;

  const int lane = t & 63;
  const int w = t >> 6;
  const int wr = (w >> 1) * 64;
  const int wc = (w & 1) * 64;
  const int ln15 = lane & 15;
  const int lk = lane >> 4;  // 0..3

  f32x4 acc[4][4];
#pragma unroll
  for (int i = 0; i < 4; ++i)
#pragma unroll
    for (int j = 0; j < 4; ++j) acc[i][j] = (f32x4){0.f, 0.f, 0.f, 0.f};

  float4 ra[8];
  uint4 rbh[4], rbl[4];

  // prologue: load K-tile 0 into regs
#pragma unroll
  for (int i = 0; i < 8; ++i) {
    const int id2 = t + i * 256;
    ra[i] = *(const float4*)&A[(size_t)(m0 + (id2 >> 4)) * 512 + ((id2 & 15) << 2)];
  }
#pragma unroll
  for (int i = 0; i < 4; ++i) {
    const int id2 = t + i * 256;
    const size_t g = (size_t)(n0 + (id2 >> 3)) * 512 + ((id2 & 7) << 3);
    rbh[i] = *(const uint4*)&Wh[g];
    rbl[i] = *(const uint4*)&Wl[g];
  }

  for (int k0 = 0; k0 < 512; k0 += 64) {
    // ---- store staged regs to LDS (split A to hi/lo here) ----
#pragma unroll
    for (int i = 0; i < 8; ++i) {
      const int id2 = t + i * 256;
      const int row = id2 >> 4;
      const int kq = (id2 & 15) << 2;
      uint2 hi, lo;
      split4(ra[i], hi, lo);
      const int c = (kq << 1) ^ ((row & 7) << 4);
      char* p = (char*)lA + row * 128 + c;
      *(uint2*)p = hi;
      *(uint2*)(p + 16384) = lo;
    }
#pragma unroll
    for (int i = 0; i < 4; ++i) {
      const int id2 = t + i * 256;
      const int row = id2 >> 3;
      const int kq = (id2 & 7) << 3;
      const int c = (kq << 1) ^ ((row & 7) << 4);
      *(uint4*)((char*)lB + row * 128 + c) = rbh[i];
      *(uint4*)((char*)lB + 16384 + row * 128 + c) = rbl[i];
    }
    __syncthreads();
    // ---- issue next tile's global loads (latency hides under MFMA) ----
    if (k0 + 64 < 512) {
      const int kn = k0 + 64;
#pragma unroll
      for (int i = 0; i < 8; ++i) {
        const int id2 = t + i * 256;
        ra[i] = *(const float4*)&A[(size_t)(m0 + (id2 >> 4)) * 512 + kn + ((id2 & 15) << 2)];
      }
#pragma unroll
      for (int i = 0; i < 4; ++i) {
        const int id2 = t + i * 256;
        const size_t g = (size_t)(n0 + (id2 >> 3)) * 512 + kn + ((id2 & 7) << 3);
        rbh[i] = *(const uint4*)&Wh[g];
        rbl[i] = *(const uint4*)&Wl[g];
      }
    }
    // ---- MFMA on current LDS tile ----
#pragma unroll
    for (int ks = 0; ks < 2; ++ks) {
      bf16x8 ah[4], al[4], bh[4], bl[4];
      const int kb = ks * 64 + lk * 16;   // byte offset of this lane's 8 bf16
#pragma unroll
      for (int ff = 0; ff < 4; ++ff) {
        const int ra2 = wr + ff * 16 + ln15;
        const int ca = kb ^ ((ra2 & 7) << 4);
        ah[ff] = *(const bf16x8*)((const char*)lA + ra2 * 128 + ca);
        al[ff] = *(const bf16x8*)((const char*)lA + 16384 + ra2 * 128 + ca);
        const int rb = wc + ff * 16 + ln15;
        const int cb = kb ^ ((rb & 7) << 4);
        bh[ff] = *(const bf16x8*)((const char*)lB + rb * 128 + cb);
        bl[ff] = *(const bf16x8*)((const char*)lB + 16384 + rb * 128 + cb);
      }
#pragma unroll
      for (int fm = 0; fm < 4; ++fm)
#pragma unroll
        for (int fn = 0; fn < 4; ++fn) {
          acc[fm][fn] = __builtin_amdgcn_mfma_f32_16x16x32_bf16(
              ah[fm], bh[fn], acc[fm][fn], 0, 0, 0);
          acc[fm][fn] = __builtin_amdgcn_mfma_f32_16x16x32_bf16(
              al[fm], bh[fn], acc[fm][fn], 0, 0, 0);
          acc[fm][fn] = __builtin_amdgcn_mfma_f32_16x16x32_bf16(
              ah[fm], bl[fn], acc[fm][fn], 0, 0, 0);
        }
    }
    __syncthreads();
  }

  // ---- epilogue: C/D map col=lane&15, row=(lane>>4)*4+j (m89/m91) ----
#pragma unroll
  for (int fm = 0; fm < 4; ++fm) {
#pragma unroll
    for (int j = 0; j < 4; ++j) {
      const int row = m0 + wr + fm * 16 + lk * 4 + j;
#pragma unroll
      for (int fn = 0; fn < 4; ++fn) {
        const int col = n0 + wc + fn * 16 + ln15;
        float r = acc[fm][fn][j];
        if (clip) r = fminf(fmaxf(r, 0.f), 6.f);
        if (bias) r += bias[col];
        if (Add) r += Add[(size_t)row * 512 + col];
        Co[(size_t)row * 512 + col] = r;
      }
    }
  }
}

// ---------------------------------------------------------------------------
// MFMA attention: one block per (n, head). Q,K,V token-major fp32 [73728,512].
// scores = (Qh@Kh^T)/8 via split-bf16 3-term MFMA; pair-per-row softmax with
// in-place P->bf16 hi/lo conversion; O = P@V via MFMA with V^T staged hi/lo
// in two 32-d halves. LDS = exactly 64KB.
// ---------------------------------------------------------------------------
__global__ __launch_bounds__(256) void attn_mfma_k(const float* __restrict__ Q,
                                                   const float* __restrict__ Km,
                                                   const float* __restrict__ Vm,
                                                   float* __restrict__ O) {
  __shared__ __align__(16) char smem[65536];
  const int n = blockIdx.x;
  const int hd = blockIdx.y;
  const int t = threadIdx.x;
  const size_t abase = (size_t)n * 96 * 512 + (size_t)hd * 64;
  const int lane = t & 63;
  const int w = t >> 6;
  const int ln15 = lane & 15;
  const int g = lane >> 4;        // 0..3
  const int wr = (w >> 1) * 48;   // wave row base (48 rows)
  const int wcs = (w & 1) * 48;   // wave col base for scores
  const int wcp = (w & 1) * 16;   // wave col base within a 32-d PV half

  // ---- phase 1: stage Q,K hi/lo + V^T half 0 ----
#pragma unroll
  for (int i = 0; i < 6; ++i) {
    const int idx = t + i * 256;          // < 1536
    const int row = idx >> 4;             // 0..95
    const int kq = (idx & 15) << 2;       // 0..60
    const int c = (kq << 1) ^ ((row & 7) << 4);
    uint2 hi, lo;
    float4 v = *(const float4*)&Q[abase + (size_t)row * 512 + kq];
    split4(v, hi, lo);
    *(uint2*)(smem + row * 128 + c) = hi;
    *(uint2*)(smem + 12288 + row * 128 + c) = lo;
    v = *(const float4*)&Km[abase + (size_t)row * 512 + kq];
    split4(v, hi, lo);
    *(uint2*)(smem + 24576 + row * 128 + c) = hi;
    *(uint2*)(smem + 36864 + row * 128 + c) = lo;
  }
  // V^T half 0 (d 0..31): vt[d][j]
#pragma unroll
  for (int i = 0; i < 6; ++i) {
    const int j = (t >> 4) + i * 16;      // 0..95
    const int dl = (t & 15) << 1;         // 0,2,..,30
    const float2 v = *(const float2*)&Vm[abase + (size_t)j * 512 + dl];
    const uint u0 = __float_as_uint(v.x), u1 = __float_as_uint(v.y);
    const ushort h0 = (ushort)(u0 >> 16), h1 = (ushort)(u1 >> 16);
    const ushort l0 = (ushort)bf16rn(v.x - __uint_as_float(u0 & 0xffff0000u));
    const ushort l1 = (ushort)bf16rn(v.y - __uint_as_float(u1 & 0xffff0000u));
    const int c0 = (j << 1) ^ ((dl & 7) << 4);
    const int c1 = (j << 1) ^ (((dl + 1) & 7) << 4);
    *(ushort*)(smem + 49152 + dl * 256 + c0) = h0;
    *(ushort*)(smem + 57344 + dl * 256 + c0) = l0;
    *(ushort*)(smem + 49152 + (dl + 1) * 256 + c1) = h1;
    *(ushort*)(smem + 57344 + (dl + 1) * 256 + c1) = l1;
  }
  __syncthreads();

  // ---- phase 2: scores = Q @ K^T (3-term split), 48x48 per wave ----
  f32x4 acc[3][3];
#pragma unroll
  for (int i = 0; i < 3; ++i)
#pragma unroll
    for (int j = 0; j < 3; ++j) acc[i][j] = (f32x4){0.f, 0.f, 0.f, 0.f};
#pragma unroll
  for (int ks = 0; ks < 2; ++ks) {
    const int kb = ks * 64 + g * 16;
    bf16x8 ah[3], al[3], bh[3], bl[3];
#pragma unroll
    for (int ff = 0; ff < 3; ++ff) {
      const int ra = wr + ff * 16 + ln15;
      const int ca = kb ^ ((ra & 7) << 4);
      ah[ff] = *(const bf16x8*)(smem + ra * 128 + ca);
      al[ff] = *(const bf16x8*)(smem + 12288 + ra * 128 + ca);
      const int rb = wcs + ff * 16 + ln15;
      const int cb = kb ^ ((rb & 7) << 4);
      bh[ff] = *(const bf16x8*)(smem + 24576 + rb * 128 + cb);
      bl[ff] = *(const bf16x8*)(smem + 36864 + rb * 128 + cb);
    }
#pragma unroll
    for (int fm = 0; fm < 3; ++fm)
#pragma unroll
      for (int fn = 0; fn < 3; ++fn) {
        acc[fm][fn] = __builtin_amdgcn_mfma_f32_16x16x32_bf16(
            ah[fm], bh[fn], acc[fm][fn], 0, 0, 0);
        acc[fm][fn] = __builtin_amdgcn_mfma_f32_16x16x32_bf16(
            al[fm], bh[fn], acc[fm][fn], 0, 0, 0);
        acc[fm][fn] = __builtin_amdgcn_mfma_f32_16x16x32_bf16(
            ah[fm], bl[fn], acc[fm][fn], 0, 0, 0);
      }
  }
  __syncthreads();  // Q/K LDS dead; region becomes ss/P

  // ---- phase 3: scaled scores -> ss fp32 (row stride 512B) ----
#pragma unroll
  for (int fm = 0; fm < 3; ++fm)
#pragma unroll
    for (int j = 0; j < 4; ++j) {
      const int row = wr + fm * 16 + g * 4 + j;
#pragma unroll
      for (int fn = 0; fn < 3; ++fn) {
        const int col = wcs + fn * 16 + ln15;
        *(float*)(smem + row * 512 + col * 4) = acc[fm][fn][j] * 0.125f;
      }
    }
  __syncthreads();

  // ---- phase 4: softmax (2 threads/row, same wave) + in-place P hi/lo ----
  if (t < 192) {
    const int row = t >> 1;
    const int hf = t & 1;
    float v[48];
    const char* rp = smem + row * 512 + hf * 192;
#pragma unroll
    for (int i = 0; i < 12; ++i) *(float4*)&v[i * 4] = *(const float4*)(rp + i * 16);
    float mx = v[0];
#pragma unroll
    for (int i = 1; i < 48; ++i) mx = fmaxf(mx, v[i]);
    mx = fmaxf(mx, __shfl_xor(mx, 1));
    float s = 0.f;
#pragma unroll
    for (int i = 0; i < 48; ++i) { v[i] = __expf(v[i] - mx); s += v[i]; }
    s += __shfl_xor(s, 1);
    const float inv = 1.f / s;
    const int sw = (row & 7) << 4;
#pragma unroll
    for (int c = 0; c < 6; ++c) {
      uint hw[4], lw[4];
#pragma unroll
      for (int q = 0; q < 4; ++q) {
        const float p0 = v[c * 8 + q * 2] * inv;
        const float p1 = v[c * 8 + q * 2 + 1] * inv;
        const uint u0 = __float_as_uint(p0), u1 = __float_as_uint(p1);
        hw[q] = (u0 >> 16) | (u1 & 0xffff0000u);
        const float l0 = p0 - __uint_as_float(u0 & 0xffff0000u);
        const float l1 = p1 - __uint_as_float(u1 & 0xffff0000u);
        lw[q] = bf16rn(l0) | (bf16rn(l1) << 16);
      }
      const int kb = hf * 96 + c * 16;
      *(uint4*)(smem + row * 512 + (kb ^ sw)) =
          make_uint4(hw[0], hw[1], hw[2], hw[3]);
      *(uint4*)(smem + row * 512 + 256 + (kb ^ sw)) =
          make_uint4(lw[0], lw[1], lw[2], lw[3]);
    }
  }
  __syncthreads();

  // ---- phase 5/6: O = P @ V in two 32-d halves ----
  for (int h = 0; h < 2; ++h) {
    if (h == 1) {
      __syncthreads();  // PV half-0 vt reads done
#pragma unroll
      for (int i = 0; i < 6; ++i) {
        const int j = (t >> 4) + i * 16;
        const int dl = (t & 15) << 1;
        const float2 v = *(const float2*)&Vm[abase + (size_t)j * 512 + 32 + dl];
        const uint u0 = __float_as_uint(v.x), u1 = __float_as_uint(v.y);
        const ushort h0 = (ushort)(u0 >> 16), h1 = (ushort)(u1 >> 16);
        const ushort l0 = (ushort)bf16rn(v.x - __uint_as_float(u0 & 0xffff0000u));
        const ushort l1 = (ushort)bf16rn(v.y - __uint_as_float(u1 & 0xffff0000u));
        const int c0 = (j << 1) ^ ((dl & 7) << 4);
        const int c1 = (j << 1) ^ (((dl + 1) & 7) << 4);
        *(ushort*)(smem + 49152 + dl * 256 + c0) = h0;
        *(ushort*)(smem + 57344 + dl * 256 + c0) = l0;
        *(ushort*)(smem + 49152 + (dl + 1) * 256 + c1) = h1;
        *(ushort*)(smem + 57344 + (dl + 1) * 256 + c1) = l1;
      }
      __syncthreads();
    }
    f32x4 po[3];
#pragma unroll
    for (int i = 0; i < 3; ++i) po[i] = (f32x4){0.f, 0.f, 0.f, 0.f};
#pragma unroll
    for (int ks = 0; ks < 3; ++ks) {
      const int kb = ks * 64 + g * 16;
      bf16x8 ph[3], pl[3];
#pragma unroll
      for (int fm = 0; fm < 3; ++fm) {
        const int row = wr + fm * 16 + ln15;
        const int c = kb ^ ((row & 7) << 4);
        ph[fm] = *(const bf16x8*)(smem + row * 512 + c);
        pl[fm] = *(const bf16x8*)(smem + row * 512 + 256 + c);
      }
      const int dr = wcp + ln15;
      const int cb = kb ^ ((dr & 7) << 4);
      const bf16x8 vh = *(const bf16x8*)(smem + 49152 + dr * 256 + cb);
      const bf16x8 vl = *(const bf16x8*)(smem + 57344 + dr * 256 + cb);
#pragma unroll
      for (int fm = 0; fm < 3; ++fm) {
        po[fm] = __builtin_amdgcn_mfma_f32_16x16x32_bf16(ph[fm], vh, po[fm], 0, 0, 0);
        po[fm] = __builtin_amdgcn_mfma_f32_16x16x32_bf16(pl[fm], vh, po[fm], 0, 0, 0);
        po[fm] = __builtin_amdgcn_mfma_f32_16x16x32_bf16(ph[fm], vl, po[fm], 0, 0, 0);
      }
    }
    const int d = h * 32 + wcp + ln15;
#pragma unroll
    for (int fm = 0; fm < 3; ++fm)
#pragma unroll
      for (int j = 0; j < 4; ++j) {
        const int row = wr + fm * 16 + g * 4 + j;
        O[abase + (size_t)row * 512 + d] = po[fm][j];
      }
  }
}

// ---------------------------------------------------------------------------
// Depthwise 3x3 (SAME) + BatchNorm(eval): y in bchw layout
// ---------------------------------------------------------------------------
__global__ __launch_bounds__(256) void dwconv_bn_k(const float* __restrict__ x,
                                                   const float* __restrict__ w9,
                                                   const float* __restrict__ g,
                                                   const float* __restrict__ bta,
                                                   const float* __restrict__ mu,
                                                   const float* __restrict__ var,
                                                   float* __restrict__ y) {
  const int idx = blockIdx.x * 256 + threadIdx.x;  // < 37748736
  const int wq = idx % 96;
  const int r1 = idx / 96;
  const int hq = r1 % 96;
  const int c = (r1 / 96) & 511;
  const int bq = idx / 4718592;
  const float* xb = x + ((size_t)bq * NC + c) * HWSZ;
  const float* wc = w9 + c * 9;
  float acc = 0.f;
#pragma unroll
  for (int di = -1; di <= 1; ++di) {
    const int h2 = hq + di;
    if (h2 < 0 || h2 > 95) continue;
#pragma unroll
    for (int dj = -1; dj <= 1; ++dj) {
      const int w2 = wq + dj;
      if (w2 < 0 || w2 > 95) continue;
      acc += xb[h2 * 96 + w2] * wc[(di + 1) * 3 + (dj + 1)];
    }
  }
  const float scl = g[c] / sqrtf(var[c] + 1e-5f);
  y[idx] = (acc - mu[c]) * scl + bta[c];
}

// ---------------------------------------------------------------------------
// Schedule (4 ws buffers of 151MB; weight hi/lo splits live in d_out until the
// final transpose overwrites it):
//  w0: Xt(1-5r) -> xp(7w,8r) -> CR(10w,13r)
//  w1: K(2w,4r) -> KV2(5w,9r) -> YdwTok(12w,13r)
//  w2: V(3w,4r) -> O1(6w,7r) -> A2(9w,10r) -> OutTok(13w,14r)
//  w3: A1(4w,6r) -> Q2(8w,9r) -> Ydw bchw(11w,12r)
// ---------------------------------------------------------------------------
extern "C" void kernel_launch(void* const* d_in, const int* in_sizes, int n_in,
                              void* d_out, int out_size, void* d_ws, size_t ws_size,
                              hipStream_t stream) {
  const float* x   = (const float*)d_in[0];
  const float* Wk  = (const float*)d_in[1];
  const float* Wv  = (const float*)d_in[2];
  const float* Wo  = (const float*)d_in[3];
  const float* cWq = (const float*)d_in[4];
  const float* cbq = (const float*)d_in[5];
  const float* cWv = (const float*)d_in[6];
  const float* cWo = (const float*)d_in[7];
  const float* dw  = (const float*)d_in[8];
  const float* bng = (const float*)d_in[9];
  const float* bnb = (const float*)d_in[10];
  const float* bnm = (const float*)d_in[11];
  const float* bnv = (const float*)d_in[12];
  const float* pw  = (const float*)d_in[13];
  float* out = (float*)d_out;
  float* ws = (float*)d_ws;

  const size_t SZ = (size_t)MTOK * NC;
  float* w0 = ws;
  float* w1 = ws + SZ;
  float* w2 = ws + 2 * SZ;
  float* w3 = ws + 3 * SZ;

  // weight hi/lo area: 7 matrices x 1MB, parked in d_out (dead until step 14)
  ushort* wx = (ushort*)d_out;
  const size_t WME = 524288;  // ushorts per matrix (hi+lo)
#define WH(i) (wx + (i) * WME)
#define WL(i) (wx + (i) * WME + 262144)

  const dim3 tb(32, 8);
  const dim3 tg(48, 96, 8);       // transposes
  const dim3 gg(4, 576);          // MFMA gemm (remapped XCD-aware in-kernel)

  // 0. split weights to bf16 hi/lo:  0=Wk 1=Wv 2=Wo 3=cWq 4=cWv 5=cWo 6=pw
  wext_k<<<dim3(256, 7), 256, 0, stream>>>(Wk, Wv, Wo, cWq, cWv, cWo, pw, wx);
  // 1. vqk tokens: w0 = Xt
  bchw_to_tok_k<<<tg, tb, 0, stream>>>(x, w0);
  // 2. K = Xt@Wk^T + Xt -> w1
  gemm_mfma_k<<<gg, 256, 0, stream>>>(w0, WH(0), WL(0), w0, nullptr, w1, 0);
  // 3. V = Xt@Wv^T -> w2
  gemm_mfma_k<<<gg, 256, 0, stream>>>(w0, WH(1), WL(1), nullptr, nullptr, w2, 0);
  // 4. MSA attention (q = Xt) -> w3 = A1
  attn_mfma_k<<<dim3(768, 8), 256, 0, stream>>>(w0, w1, w2, w3);
  // 5. KV2 = Xt@cWv^T -> w1  (K dead; Xt last read here)
  gemm_mfma_k<<<gg, 256, 0, stream>>>(w0, WH(4), WL(4), nullptr, nullptr, w1, 0);
  // 6. O1 = A1@Wo^T -> w2  (V dead)
  gemm_mfma_k<<<gg, 256, 0, stream>>>(w3, WH(2), WL(2), nullptr, nullptr, w2, 0);
  // 7. odd reshape: xp[b,c,h,w] = O1 tokens -> w0  (Xt dead)
  tok_to_bchw_k<<<tg, tb, 0, stream>>>(w2, w0);
  // 8. Q2 = xp_flat@cWq^T + bq -> w3  (A1 dead)
  gemm_mfma_k<<<gg, 256, 0, stream>>>(w0, WH(3), WL(3), nullptr, cbq, w3, 0);
  // 9. Cross attention (q=Q2, k=v=KV2) -> w2  (O1 dead)
  attn_mfma_k<<<dim3(768, 8), 256, 0, stream>>>(w3, w1, w1, w2);
  // 10. CR = A2@cWo^T -> w0  (xp dead)
  gemm_mfma_k<<<gg, 256, 0, stream>>>(w2, WH(5), WL(5), nullptr, nullptr, w0, 0);
  // 11. depthwise conv + BN -> w3 bchw  (Q2 dead)
  dwconv_bn_k<<<147456, 256, 0, stream>>>(x, dw, bng, bnb, bnm, bnv, w3);
  // 12. Ydw tokens -> w1  (KV2 dead)
  bchw_to_tok_k<<<tg, tb, 0, stream>>>(w3, w1);
  // 13. OutTok = clip(YdwTok@pw^T) + CR -> w2  (A2 dead)
  gemm_mfma_k<<<gg, 256, 0, stream>>>(w1, WH(6), WL(6), w0, nullptr, w2, 1);
  // 14. OutTok -> bchw d_out  (weight area dead)
  tok_to_bchw_k<<<tg, tb, 0, stream>>>(w2, out);
}